// Round 1
// baseline (12469.902 us; speedup 1.0000x reference)
//
#include <hip/hip_runtime.h>

// ---------------------------------------------------------------------------
// get_aligned_feat: 4x (3x3 offset conv -> deformable conv 3x3, pad 1) cascade
// B=8, H=W=96, C=64. Block1 input = concat(fr, ft) (implicit, two pointers).
// Round 0: correctness-first direct kernels. fp32 throughout.
// ---------------------------------------------------------------------------

#define HH 96
#define WW 96
#define HWSZ (HH * WW)
#define BB 8

// Direct 3x3 conv, stride 1, pad 1, no bias.
// Input channels = Ca (from inA) followed by Cb (from inB) -> implicit concat.
// Thread = one output element, idx = ((b*outC + oc)*H + y)*W + x.
__global__ void conv3_kernel(const float* __restrict__ inA,
                             const float* __restrict__ inB,
                             int Ca, int Cb,
                             const float* __restrict__ w,
                             float* __restrict__ out,
                             int outC) {
    int idx = blockIdx.x * blockDim.x + threadIdx.x;
    int total = BB * outC * HWSZ;
    if (idx >= total) return;
    int x  = idx % WW;
    int y  = (idx / WW) % HH;
    int oc = (idx / HWSZ) % outC;
    int b  = idx / (HWSZ * outC);
    int C  = Ca + Cb;

    float acc = 0.f;
    const float* wp = w + (size_t)oc * C * 9;   // [outC][C][3][3]
    for (int ic = 0; ic < C; ++ic) {
        const float* ip = (ic < Ca)
            ? inA + ((size_t)b * Ca + ic) * HWSZ
            : inB + ((size_t)b * Cb + (ic - Ca)) * HWSZ;
        const float* wk = wp + ic * 9;
#pragma unroll
        for (int ky = 0; ky < 3; ++ky) {
            int iy = y + ky - 1;
            if (iy < 0 || iy >= HH) continue;
            const float* row = ip + iy * WW;
#pragma unroll
            for (int kx = 0; kx < 3; ++kx) {
                int ix = x + kx - 1;
                if (ix < 0 || ix >= WW) continue;
                acc += row[ix] * wk[ky * 3 + kx];
            }
        }
    }
    out[idx] = acc;
}

// Deformable conv 3x3, stride 1, pad 1, dilation 1.
// offset channels = G*18, layout [G][K=9][2(y,x)][H][W].
// weight [outC][Cg][3][3], conv groups == offset groups == G.
// Input channels: Ca from xA then Cb from xB (implicit concat).
// Thread = one output element.
__global__ void deform_kernel(const float* __restrict__ xA,
                              const float* __restrict__ xB,
                              int Ca, int Cb,
                              const float* __restrict__ off,
                              const float* __restrict__ w,
                              const float* __restrict__ bias,
                              float* __restrict__ out,
                              int G, int outC) {
    int idx = blockIdx.x * blockDim.x + threadIdx.x;
    int total = BB * outC * HWSZ;
    if (idx >= total) return;
    int x  = idx % WW;
    int y  = (idx / WW) % HH;
    int oc = (idx / HWSZ) % outC;
    int b  = idx / (HWSZ * outC);

    int C     = Ca + Cb;
    int Cg    = C / G;
    int outCg = outC / G;
    int g     = oc / outCg;
    int offC  = G * 18;

    const float* offp = off + ((size_t)b * offC) * HWSZ + (size_t)y * WW + x;
    const float* wp   = w + (size_t)oc * Cg * 9;   // [outC][Cg][9]
    float acc = bias[oc];

#pragma unroll
    for (int k = 0; k < 9; ++k) {
        int ky = k / 3, kx = k % 3;
        float offy = offp[(size_t)((g * 9 + k) * 2 + 0) * HWSZ];
        float offx = offp[(size_t)((g * 9 + k) * 2 + 1) * HWSZ];
        float py = offy + (float)(y - 1 + ky);
        float px = offx + (float)(x - 1 + kx);
        float fy0 = floorf(py), fx0 = floorf(px);
        float wy = py - fy0, wx = px - fx0;
        int y0 = (int)fy0, x0 = (int)fx0;
        int y1 = y0 + 1,  x1 = x0 + 1;
        bool vy0 = (y0 >= 0) && (y0 < HH);
        bool vy1 = (y1 >= 0) && (y1 < HH);
        bool vx0 = (x0 >= 0) && (x0 < WW);
        bool vx1 = (x1 >= 0) && (x1 < WW);
        int cy0 = min(max(y0, 0), HH - 1), cy1 = min(max(y1, 0), HH - 1);
        int cx0 = min(max(x0, 0), WW - 1), cx1 = min(max(x1, 0), WW - 1);
        float w00 = (1.f - wy) * (1.f - wx) * ((vy0 && vx0) ? 1.f : 0.f);
        float w01 = (1.f - wy) * wx         * ((vy0 && vx1) ? 1.f : 0.f);
        float w10 = wy * (1.f - wx)         * ((vy1 && vx0) ? 1.f : 0.f);
        float w11 = wy * wx                 * ((vy1 && vx1) ? 1.f : 0.f);
        int i00 = cy0 * WW + cx0, i01 = cy0 * WW + cx1;
        int i10 = cy1 * WW + cx0, i11 = cy1 * WW + cx1;

        for (int c = 0; c < Cg; ++c) {
            int cc = g * Cg + c;
            const float* p = (cc < Ca)
                ? xA + ((size_t)b * Ca + cc) * HWSZ
                : xB + ((size_t)b * Cb + (cc - Ca)) * HWSZ;
            float v = w00 * p[i00] + w01 * p[i01] + w10 * p[i10] + w11 * p[i11];
            acc += v * wp[c * 9 + k];
        }
    }
    out[idx] = acc;
}

static inline int nblk(long n) { return (int)((n + 255) / 256); }

extern "C" void kernel_launch(void* const* d_in, const int* in_sizes, int n_in,
                              void* d_out, int out_size, void* d_ws, size_t ws_size,
                              hipStream_t stream) {
    const float* fr     = (const float*)d_in[0];
    const float* ft     = (const float*)d_in[1];
    const float* off1_w = (const float*)d_in[2];
    const float* def1_w = (const float*)d_in[3];
    const float* def1_b = (const float*)d_in[4];
    const float* off2_w = (const float*)d_in[5];
    const float* def2_w = (const float*)d_in[6];
    const float* def2_b = (const float*)d_in[7];
    const float* off3_w = (const float*)d_in[8];
    const float* def3_w = (const float*)d_in[9];
    const float* def3_b = (const float*)d_in[10];
    const float* off4_w = (const float*)d_in[11];
    const float* def4_w = (const float*)d_in[12];
    const float* def4_b = (const float*)d_in[13];
    float* outp = (float*)d_out;

    // workspace layout (floats): off[8*72*9216] | fA[8*64*9216] | fB[8*64*9216]
    float* off = (float*)d_ws;
    float* fA  = off + (size_t)BB * 72 * HWSZ;
    float* fB  = fA  + (size_t)BB * 64 * HWSZ;

    dim3 blk(256);
    long n64 = (long)BB * 64 * HWSZ;
    long n72 = (long)BB * 72 * HWSZ;
    long n36 = (long)BB * 36 * HWSZ;

    // ---- block 1: input = concat(fr, ft) [B,128,H,W], G=4 ----
    conv3_kernel<<<nblk(n72), blk, 0, stream>>>(fr, ft, 64, 64, off1_w, off, 72);
    deform_kernel<<<nblk(n64), blk, 0, stream>>>(fr, ft, 64, 64, off, def1_w, def1_b, fA, 4, 64);

    // ---- block 2: input = feat1 (fA), G=4 ----
    conv3_kernel<<<nblk(n72), blk, 0, stream>>>(fA, fA, 64, 0, off2_w, off, 72);
    deform_kernel<<<nblk(n64), blk, 0, stream>>>(fA, fA, 64, 0, off, def2_w, def2_b, fB, 4, 64);

    // ---- block 3: input = feat2 (fB), G=4 ----
    conv3_kernel<<<nblk(n72), blk, 0, stream>>>(fB, fB, 64, 0, off3_w, off, 72);
    deform_kernel<<<nblk(n64), blk, 0, stream>>>(fB, fB, 64, 0, off, def3_w, def3_b, fA, 4, 64);

    // ---- block 4: offsets from feat3 (fA), sampling applied to ft, G=2 ----
    conv3_kernel<<<nblk(n36), blk, 0, stream>>>(fA, fA, 64, 0, off4_w, off, 36);
    deform_kernel<<<nblk(n64), blk, 0, stream>>>(ft, ft, 64, 0, off, def4_w, def4_b, outp, 2, 64);
}

// Round 2
// 1385.621 us; speedup vs baseline: 8.9995x; 8.9995x over previous
//
#include <hip/hip_runtime.h>

// ---------------------------------------------------------------------------
// get_aligned_feat: 4x (3x3 offset conv -> deformable conv 3x3, pad 1) cascade
// B=8, H=W=96, C=64. Block1 input = concat(fr, ft) (implicit, two pointers).
// Round 1: register-reuse restructure.
//   - deform: thread = (b, g, pixel), computes all outCg outputs; bilinear
//     gather done ONCE per (c,k) instead of outCg times. Weight reads are
//     wave-uniform (g from blockIdx.y) -> scalar s_loads.
//   - conv3: thread = (b, oc-tile, pixel), computes OCT output channels,
//     input taps loaded once per ic and reused OCT times.
// ---------------------------------------------------------------------------

#define HH 96
#define WW 96
#define HWSZ (HH * WW)
#define BB 8

// ---------------- direct 3x3 conv, OCT output channels per thread ----------
template <int OCT>
__global__ __launch_bounds__(256) void conv3b_kernel(
    const float* __restrict__ xA, const float* __restrict__ xB,
    int Ca, int Cb,
    const float* __restrict__ w,
    float* __restrict__ out, int outC)
{
    int pix = blockIdx.x * 256 + threadIdx.x;   // 36 blocks * 256 = 9216 = HW
    int oc0 = blockIdx.y * OCT;
    int b   = blockIdx.z;
    int x = pix % WW, y = pix / WW;
    int C = Ca + Cb;

    int   idx9[9];
    float msk9[9];
#pragma unroll
    for (int k = 0; k < 9; ++k) {
        int ky = k / 3, kx = k % 3;
        int iy = y + ky - 1, ix = x + kx - 1;
        bool ok = (iy >= 0) && (iy < HH) && (ix >= 0) && (ix < WW);
        int cy = min(max(iy, 0), HH - 1);
        int cx = min(max(ix, 0), WW - 1);
        idx9[k] = cy * WW + cx;
        msk9[k] = ok ? 1.f : 0.f;
    }

    float acc[OCT];
#pragma unroll
    for (int o = 0; o < OCT; ++o) acc[o] = 0.f;

    for (int ic = 0; ic < C; ++ic) {
        const float* p = (ic < Ca)
            ? xA + ((size_t)b * Ca + ic) * HWSZ
            : xB + ((size_t)b * Cb + (ic - Ca)) * HWSZ;
        float t[9];
#pragma unroll
        for (int k = 0; k < 9; ++k) t[k] = msk9[k] * p[idx9[k]];
        const float* wic = w + ((size_t)oc0 * C + ic) * 9;
#pragma unroll
        for (int o = 0; o < OCT; ++o) {
            const float* wo = wic + (size_t)o * C * 9;   // wave-uniform -> s_load
#pragma unroll
            for (int k = 0; k < 9; ++k) acc[o] += t[k] * wo[k];
        }
    }

    float* op = out + ((size_t)b * outC + oc0) * HWSZ + pix;
#pragma unroll
    for (int o = 0; o < OCT; ++o) op[(size_t)o * HWSZ] = acc[o];
}

// ---------------- deformable conv: thread = (b,g,pixel), all outCg outputs --
template <int CG, int OCG>
__global__ __launch_bounds__(256) void deform2_kernel(
    const float* __restrict__ xA, const float* __restrict__ xB,
    int Ca, int Cb,
    const float* __restrict__ off,
    const float* __restrict__ w,
    const float* __restrict__ bias,
    float* __restrict__ out,
    int G, int outC)
{
    int pix = blockIdx.x * 256 + threadIdx.x;
    int g   = blockIdx.y;                       // wave-uniform
    int b   = blockIdx.z;
    int x = pix % WW, y = pix / WW;

    const float* offp = off + ((size_t)(b * G + g) * 18) * HWSZ + pix;

    // precompute bilinear weights (validity folded in) + corner indices, per k
    float bw0[9], bw1[9], bw2[9], bw3[9];
    int   bi0[9], bi1[9], bi2[9], bi3[9];
#pragma unroll
    for (int k = 0; k < 9; ++k) {
        int ky = k / 3, kx = k % 3;
        float offy = offp[(size_t)(2 * k + 0) * HWSZ];
        float offx = offp[(size_t)(2 * k + 1) * HWSZ];
        float py = offy + (float)(y - 1 + ky);
        float px = offx + (float)(x - 1 + kx);
        float fy0 = floorf(py), fx0 = floorf(px);
        float wy = py - fy0, wx = px - fx0;
        int y0 = (int)fy0, x0 = (int)fx0;
        int y1 = y0 + 1,  x1 = x0 + 1;
        bool vy0 = (y0 >= 0) && (y0 < HH);
        bool vy1 = (y1 >= 0) && (y1 < HH);
        bool vx0 = (x0 >= 0) && (x0 < WW);
        bool vx1 = (x1 >= 0) && (x1 < WW);
        int cy0 = min(max(y0, 0), HH - 1), cy1 = min(max(y1, 0), HH - 1);
        int cx0 = min(max(x0, 0), WW - 1), cx1 = min(max(x1, 0), WW - 1);
        bw0[k] = (1.f - wy) * (1.f - wx) * ((vy0 && vx0) ? 1.f : 0.f);
        bw1[k] = (1.f - wy) * wx         * ((vy0 && vx1) ? 1.f : 0.f);
        bw2[k] = wy * (1.f - wx)         * ((vy1 && vx0) ? 1.f : 0.f);
        bw3[k] = wy * wx                 * ((vy1 && vx1) ? 1.f : 0.f);
        bi0[k] = cy0 * WW + cx0;  bi1[k] = cy0 * WW + cx1;
        bi2[k] = cy1 * WW + cx0;  bi3[k] = cy1 * WW + cx1;
    }

    float acc[OCG];
#pragma unroll
    for (int o = 0; o < OCG; ++o) acc[o] = bias[g * OCG + o];  // uniform -> s_load

    const float* wg = w + (size_t)g * OCG * CG * 9;            // wave-uniform base
    for (int c = 0; c < CG; ++c) {
        int cc = g * CG + c;
        const float* p = (cc < Ca)
            ? xA + ((size_t)b * Ca + cc) * HWSZ
            : xB + ((size_t)b * Cb + (cc - Ca)) * HWSZ;
        float v[9];
#pragma unroll
        for (int k = 0; k < 9; ++k)
            v[k] = bw0[k] * p[bi0[k]] + bw1[k] * p[bi1[k]]
                 + bw2[k] * p[bi2[k]] + bw3[k] * p[bi3[k]];
        const float* wc = wg + c * 9;
#pragma unroll
        for (int o = 0; o < OCG; ++o) {
            const float* wo = wc + (size_t)o * CG * 9;   // uniform, 9 contiguous
#pragma unroll
            for (int k = 0; k < 9; ++k) acc[o] += v[k] * wo[k];
        }
    }

    float* op = out + ((size_t)b * outC + (size_t)g * OCG) * HWSZ + pix;
#pragma unroll
    for (int o = 0; o < OCG; ++o) op[(size_t)o * HWSZ] = acc[o];
}

extern "C" void kernel_launch(void* const* d_in, const int* in_sizes, int n_in,
                              void* d_out, int out_size, void* d_ws, size_t ws_size,
                              hipStream_t stream) {
    const float* fr     = (const float*)d_in[0];
    const float* ft     = (const float*)d_in[1];
    const float* off1_w = (const float*)d_in[2];
    const float* def1_w = (const float*)d_in[3];
    const float* def1_b = (const float*)d_in[4];
    const float* off2_w = (const float*)d_in[5];
    const float* def2_w = (const float*)d_in[6];
    const float* def2_b = (const float*)d_in[7];
    const float* off3_w = (const float*)d_in[8];
    const float* def3_w = (const float*)d_in[9];
    const float* def3_b = (const float*)d_in[10];
    const float* off4_w = (const float*)d_in[11];
    const float* def4_w = (const float*)d_in[12];
    const float* def4_b = (const float*)d_in[13];
    float* outp = (float*)d_out;

    // workspace layout (floats): off[8*72*9216] | fA[8*64*9216] | fB[8*64*9216]
    float* off = (float*)d_ws;
    float* fA  = off + (size_t)BB * 72 * HWSZ;
    float* fB  = fA  + (size_t)BB * 64 * HWSZ;

    dim3 blk(256);
    dim3 gConv72(36, 9, BB);   // OCT=8  -> 72 channels
    dim3 gConv36(36, 9, BB);   // OCT=4  -> 36 channels
    dim3 gDefG4(36, 4, BB);
    dim3 gDefG2(36, 2, BB);

    // ---- block 1: input = concat(fr, ft) [B,128,H,W], G=4, Cg=32, outCg=16
    conv3b_kernel<8><<<gConv72, blk, 0, stream>>>(fr, ft, 64, 64, off1_w, off, 72);
    deform2_kernel<32, 16><<<gDefG4, blk, 0, stream>>>(fr, ft, 64, 64, off, def1_w, def1_b, fA, 4, 64);

    // ---- block 2: input = feat1 (fA), G=4, Cg=16, outCg=16
    conv3b_kernel<8><<<gConv72, blk, 0, stream>>>(fA, fA, 64, 0, off2_w, off, 72);
    deform2_kernel<16, 16><<<gDefG4, blk, 0, stream>>>(fA, fA, 64, 0, off, def2_w, def2_b, fB, 4, 64);

    // ---- block 3: input = feat2 (fB), G=4, Cg=16, outCg=16
    conv3b_kernel<8><<<gConv72, blk, 0, stream>>>(fB, fB, 64, 0, off3_w, off, 72);
    deform2_kernel<16, 16><<<gDefG4, blk, 0, stream>>>(fB, fB, 64, 0, off, def3_w, def3_b, fA, 4, 64);

    // ---- block 4: offsets from feat3 (fA), sampling applied to ft, G=2, Cg=32, outCg=32
    conv3b_kernel<4><<<gConv36, blk, 0, stream>>>(fA, fA, 64, 0, off4_w, off, 36);
    deform2_kernel<32, 32><<<gDefG2, blk, 0, stream>>>(ft, ft, 64, 0, off, def4_w, def4_b, outp, 2, 64);
}